// Round 3
// baseline (4112.737 us; speedup 1.0000x reference)
//
#include <hip/hip_runtime.h>
#include <math.h>

// Problem: B=64, T=512, I=128, H=1024, O=128; gates order i,j,f,o; relu activations.
#define Bsz 64
#define Tn  512
#define In  128
#define Hn  1024
#define KT  1152      // I + H
#define NBLK 128      // persistent blocks; each owns 8 hidden cols (x4 gates = 32 cols)

// syn (u32 word indices), each hot word on its own 128B line:
//   arrive counters: CNT(s,g) = 32*(s*8+g)        (s=row-slice 0..1, g=col-group 0..7)
//   step flags:      FLG(s,g) = 512 + 32*(s*8+g)  (value v => h(0..v-1)[slice s] visible)
// RMW lines and poll lines are SEPARATE (R2 lesson: merging them regressed).
#define CNT(s,g) (32 * ((s) * 8 + (g)))
#define FLG(s,g) (512 + 32 * ((s) * 8 + (g)))

typedef __attribute__((ext_vector_type(8))) short bf16x8;   // 8 bf16 = 4 VGPRs (MFMA A/B frag)
typedef __attribute__((ext_vector_type(4))) short s16x4;
typedef __attribute__((ext_vector_type(4))) float f32x4;
typedef __attribute__((ext_vector_type(4))) int   i32x4;

// Raw buffer store, cpol 17 = SC0|SC1 on gfx950 -> write-through to the IF/MALL
// coherence point (cross-XCD visible without any cache-walk fences). [R0-proven]
__device__ void llvm_amdgcn_raw_buffer_store_i16(short vdata, i32x4 srsrc, int voffset, int soffset, int cpol) __asm("llvm.amdgcn.raw.buffer.store.i16");

__device__ __forceinline__ i32x4 make_srd(const void* p, int bytes) {
  i32x4 r;
  r.x = (int)(unsigned)(unsigned long long)p;
  r.y = (int)((unsigned long long)p >> 32);   // stride = 0
  r.z = bytes;                                // num_records (bytes when stride==0)
  r.w = 0x00020000;                           // raw dword access
  return r;
}

__device__ __forceinline__ unsigned short f2bf(float f) {
  union { float f; unsigned u; } x; x.f = f;
  unsigned r = x.u + 0x7FFFu + ((x.u >> 16) & 1u);   // RNE
  return (unsigned short)(r >> 16);
}
__device__ __forceinline__ float sigmoidf_(float x) { return 1.0f / (1.0f + __expf(-x)); }

// ---------------- prep: X (fp32) -> Xb (bf16), elementwise ----------------
__global__ __launch_bounds__(256) void cast_x_kernel(const float* __restrict__ in,
                                                     unsigned short* __restrict__ out) {
  int i = blockIdx.x * 256 + threadIdx.x;
  f32x4 v = ((const f32x4*)in)[i];
  s16x4 o;
  o.x = (short)f2bf(v.x); o.y = (short)f2bf(v.y);
  o.z = (short)f2bf(v.z); o.w = (short)f2bf(v.w);
  ((s16x4*)out)[i] = o;
}

// -------- prep: transpose+cast fp32 [R][C] -> bf16 [C][ldo] (64x64 LDS tiles) --------
__global__ __launch_bounds__(256) void transpose_cast_kernel(const float* __restrict__ in,
                                                             unsigned short* __restrict__ out,
                                                             int R, int C, int ldo, int tilesR) {
  __shared__ unsigned short tile[64][73];
  int br = blockIdx.x % tilesR, bc = blockIdx.x / tilesR;
  int r0 = br << 6, c0 = bc << 6;
  for (int e = threadIdx.x; e < 4096; e += 256) {
    int r = e >> 6, c = e & 63;
    tile[r][c] = f2bf(in[(size_t)(r0 + r) * C + (c0 + c)]);
  }
  __syncthreads();
  for (int e = threadIdx.x; e < 4096; e += 256) {
    int c = e >> 6, r = e & 63;
    out[(size_t)(c0 + c) * ldo + (r0 + r)] = tile[r][c];
  }
}

// ---------------- persistent LSTM recurrence (barrier-free) ----------------
// Block blk owns hidden cols j in [blk*8, blk*8+8), gate cols {j, H+j, 2H+j, 3H+j}.
// 4 waves = (2 row-slices s of 32 batch rows) x (2 K-halves kh).
//   kh1: K [0,576)   = x[0,128) + h[0,448)   -> needs col-groups 0..3; x-part is poll-free.
//   kh0: K [576,1152)=            h[448,1024)-> needs col-groups 3..7; owns the epilogue.
// B-frags register-resident (144 VGPR/wave). NO __syncthreads in the step loop:
//   kh1 -> kh0 hand-off: raw per-lane partial (4x ds_write_b128, register layout,
//   elementwise add on kh0 side) + LDS seq flag. Single-buffer safe by induction:
//   kh1 reaches step t+1's Zx write only after global flags(t+1), which require
//   kh0's step-t arrive, which follows kh0's step-t Zx read.
// Global sync per row-slice (R0-proven primitives): kh0 stores h (sc0|sc1
// write-through), drains own vmcnt, lane0 fetch_adds CNT(s,grp); 16th arriver
// posts FLG(s,grp)=t+1. Consumers one-shot-ballot their 4-5 group flags.
__global__ __launch_bounds__(256, 1) void lstm_kernel(
    const unsigned short* __restrict__ Xb,    // [64][512][128] bf16
    const unsigned short* __restrict__ WkT,   // [4096][1152]  bf16 (col-major-in-k)
    const float* __restrict__ bias,           // [4096]
    unsigned short* __restrict__ hs,          // [512][64][1024] bf16 (output history)
    unsigned* __restrict__ S)                 // sync area (4 KB, zeroed)
{
  __shared__ float Zx[2][64][16];             // kh1 partials, raw per-lane layout (8 KB)
  __shared__ float Zw[2][32][33];             // kh0 gate-transpose scratch (8.25 KB)
  __shared__ unsigned FlL[2][32];             // intra-block seq flags, [s][0] used

  const int tid = threadIdx.x;
  const int blk = blockIdx.x;
  const int grp = blk >> 4;                   // col-group of this block (16 blocks/group)
  const int w   = tid >> 6;
  const int s   = w >> 1;                     // row-slice: batch rows [32s, 32s+32)
  const int kh  = w & 1;                      // 1 = low-K half, 0 = high-K half (+epilogue)
  const int l   = tid & 63, q = l >> 4, n16 = l & 15;

  const i32x4 hsrd = make_srd(hs, Tn * Bsz * Hn * 2);

  if (tid < 64) { FlL[0][tid >> 5] = 0; FlL[1][tid >> 5] = 0; }  // init seq flags
  __syncthreads();                                                // once, before loop

  // ---- load register-resident B fragments (once): 18 ks x 2 nt = 144 VGPR ----
  const int k0 = kh ? 0 : 576;                // kh1 low half, kh0 high half
  bf16x8 Bf[2][18];
#pragma unroll
  for (int nt = 0; nt < 2; ++nt) {
    int cl   = nt * 16 + n16;                                  // local col 0..31
    int gcol = (cl >> 3) * Hn + blk * 8 + (cl & 7);            // gate*1024 + j
    const unsigned short* bp = WkT + (size_t)gcol * KT + k0 + q * 8;
#pragma unroll
    for (int ks = 0; ks < 18; ++ks)
      Bf[nt][ks] = *(const bf16x8*)(bp + ks * 32);
  }

  // ---- epilogue constants (kh0): lane handles j = l&7, rows (l>>3)+8c, c=0..3 ----
  const int ej = l & 7, er = l >> 3;
  const float bi  = bias[           blk * 8 + ej];
  const float bg  = bias[    Hn   + blk * 8 + ej];
  const float bfg = bias[2 * Hn   + blk * 8 + ej] + 1.0f;      // TF forget bias
  const float bo  = bias[3 * Hn   + blk * 8 + ej];
  float cst[4] = {0.0f, 0.0f, 0.0f, 0.0f};                     // 4 cells/lane, persistent

  const int b0 = s * 32 + n16;                                 // A rows (two 16-row tiles)
  const int b1 = b0 + 16;

  for (int t = 0; t < Tn; ++t) {
    f32x4 a00 = {0,0,0,0}, a01 = {0,0,0,0}, a10 = {0,0,0,0}, a11 = {0,0,0,0};

    if (kh == 1) {
      // ---- low-K wave: x-part first (poll-free head start) ----
#pragma unroll
      for (int ks = 0; ks < 4; ++ks) {
        bf16x8 A0 = *(const bf16x8*)(Xb + ((size_t)b0 * Tn + t) * In + ks * 32 + q * 8);
        bf16x8 A1 = *(const bf16x8*)(Xb + ((size_t)b1 * Tn + t) * In + ks * 32 + q * 8);
        a00 = __builtin_amdgcn_mfma_f32_16x16x32_bf16(A0, Bf[0][ks], a00, 0, 0, 0);
        a01 = __builtin_amdgcn_mfma_f32_16x16x32_bf16(A0, Bf[1][ks], a01, 0, 0, 0);
        a10 = __builtin_amdgcn_mfma_f32_16x16x32_bf16(A1, Bf[0][ks], a10, 0, 0, 0);
        a11 = __builtin_amdgcn_mfma_f32_16x16x32_bf16(A1, Bf[1][ks], a11, 0, 0, 0);
      }
      if (t > 0) {
        // one-shot ballot wait on col-groups 0..3 of this row-slice
        for (;;) {
          unsigned f = (l < 4) ? __hip_atomic_load(&S[FLG(s, l)], __ATOMIC_RELAXED,
                                                   __HIP_MEMORY_SCOPE_AGENT)
                               : 0xFFFFFFFFu;
          if (__ballot(f >= (unsigned)t) == ~0ull) break;
          __builtin_amdgcn_s_sleep(1);
        }
        const unsigned short* hrow = hs + (size_t)(t - 1) * (Bsz * Hn);
#pragma unroll
        for (int ks = 4; ks < 18; ++ks) {
          int kcol = (ks - 4) * 32 + q * 8;                    // h cols [0,448)
          bf16x8 A0 = *(const bf16x8*)(hrow + (size_t)b0 * Hn + kcol);
          bf16x8 A1 = *(const bf16x8*)(hrow + (size_t)b1 * Hn + kcol);
          a00 = __builtin_amdgcn_mfma_f32_16x16x32_bf16(A0, Bf[0][ks], a00, 0, 0, 0);
          a01 = __builtin_amdgcn_mfma_f32_16x16x32_bf16(A0, Bf[1][ks], a01, 0, 0, 0);
          a10 = __builtin_amdgcn_mfma_f32_16x16x32_bf16(A1, Bf[0][ks], a10, 0, 0, 0);
          a11 = __builtin_amdgcn_mfma_f32_16x16x32_bf16(A1, Bf[1][ks], a11, 0, 0, 0);
        }
      }
      // ---- hand partial to kh0: raw register layout + seq flag ----
      *(f32x4*)(&Zx[s][l][ 0]) = a00;
      *(f32x4*)(&Zx[s][l][ 4]) = a01;
      *(f32x4*)(&Zx[s][l][ 8]) = a10;
      *(f32x4*)(&Zx[s][l][12]) = a11;
      asm volatile("s_waitcnt lgkmcnt(0)" ::: "memory");
      __hip_atomic_store(&FlL[s][0], (unsigned)(t + 1), __ATOMIC_RELAXED,
                         __HIP_MEMORY_SCOPE_WORKGROUP);
    } else {
      // ---- high-K wave: h cols [448,1024), groups 3..7 ----
      if (t > 0) {
        for (;;) {
          unsigned f = (l < 5) ? __hip_atomic_load(&S[FLG(s, 3 + l)], __ATOMIC_RELAXED,
                                                   __HIP_MEMORY_SCOPE_AGENT)
                               : 0xFFFFFFFFu;
          if (__ballot(f >= (unsigned)t) == ~0ull) break;
          __builtin_amdgcn_s_sleep(1);
        }
        const unsigned short* hrow = hs + (size_t)(t - 1) * (Bsz * Hn);
#pragma unroll
        for (int ks = 0; ks < 18; ++ks) {
          int kcol = 448 + ks * 32 + q * 8;                    // h cols [448,1024)
          bf16x8 A0 = *(const bf16x8*)(hrow + (size_t)b0 * Hn + kcol);
          bf16x8 A1 = *(const bf16x8*)(hrow + (size_t)b1 * Hn + kcol);
          a00 = __builtin_amdgcn_mfma_f32_16x16x32_bf16(A0, Bf[0][ks], a00, 0, 0, 0);
          a01 = __builtin_amdgcn_mfma_f32_16x16x32_bf16(A0, Bf[1][ks], a01, 0, 0, 0);
          a10 = __builtin_amdgcn_mfma_f32_16x16x32_bf16(A1, Bf[0][ks], a10, 0, 0, 0);
          a11 = __builtin_amdgcn_mfma_f32_16x16x32_bf16(A1, Bf[1][ks], a11, 0, 0, 0);
        }
      }
      // ---- combine with kh1's partial (elementwise, same lane layout) ----
      while (__hip_atomic_load(&FlL[s][0], __ATOMIC_RELAXED,
                               __HIP_MEMORY_SCOPE_WORKGROUP) < (unsigned)(t + 1)) { }
      asm volatile("" ::: "memory");
      a00 += *(const f32x4*)(&Zx[s][l][ 0]);
      a01 += *(const f32x4*)(&Zx[s][l][ 4]);
      a10 += *(const f32x4*)(&Zx[s][l][ 8]);
      a11 += *(const f32x4*)(&Zx[s][l][12]);

      // ---- transpose to (row, gate-col) layout via wave-private LDS ----
#pragma unroll
      for (int r = 0; r < 4; ++r) {
        Zw[s][     q * 4 + r][     n16] = a00[r];
        Zw[s][     q * 4 + r][16 + n16] = a01[r];
        Zw[s][16 + q * 4 + r][     n16] = a10[r];
        Zw[s][16 + q * 4 + r][16 + n16] = a11[r];
      }
      asm volatile("s_waitcnt lgkmcnt(0)" ::: "memory");

      // ---- gates + cell update: 4 cells/lane (rows er+8c, col ej) ----
#pragma unroll
      for (int c = 0; c < 4; ++c) {
        int row = er + 8 * c;
        float zi = Zw[s][row][     ej] + bi;
        float zg = Zw[s][row][ 8 + ej] + bg;
        float zf = Zw[s][row][16 + ej] + bfg;
        float zo = Zw[s][row][24 + ej] + bo;
        float ig = sigmoidf_(zi);
        float g  = fmaxf(zg, 0.0f);
        float ff = sigmoidf_(zf);
        float oo = sigmoidf_(zo);
        cst[c] = ff * cst[c] + ig * g;
        float hn = oo * fmaxf(cst[c], 0.0f);
        llvm_amdgcn_raw_buffer_store_i16((short)f2bf(hn), hsrd,
            t * (Bsz * Hn * 2) + ((s * 32 + row) * Hn + blk * 8 + ej) * 2, 0, 17);
      }
      // own-wave drain: sc1 store acks come from the coherence point -> h(t) visible
      asm volatile("s_waitcnt vmcnt(0)" ::: "memory");
      if (t < Tn - 1 && l == 0) {
        unsigned old = __hip_atomic_fetch_add(&S[CNT(s, grp)], 1u,
                                              __ATOMIC_RELAXED, __HIP_MEMORY_SCOPE_AGENT);
        if (old == 16u * (unsigned)(t + 1) - 1u)   // 16th arriver of (slice, group)
          __hip_atomic_store(&S[FLG(s, grp)], (unsigned)(t + 1),
                             __ATOMIC_RELAXED, __HIP_MEMORY_SCOPE_AGENT);
      }
    }
  }
}

// ---------------- dense epilogue: out[b,t,:] = hs_row @ Wd + bd ----------------
__global__ __launch_bounds__(256) void dense_kernel(
    const unsigned short* __restrict__ hs,    // [32768][1024] bf16, row = t*64+b
    const unsigned short* __restrict__ WdT,   // [128][1024] bf16
    const float* __restrict__ bd,             // [128]
    float* __restrict__ out)                  // [64][512][128] fp32
{
  const int tid = threadIdx.x;
  const int w = tid >> 6, l = tid & 63, q = l >> 4, n16 = l & 15;
  const int R0 = blockIdx.x * 64 + w * 16;
  f32x4 acc[8];
#pragma unroll
  for (int i = 0; i < 8; ++i) acc[i] = (f32x4){0, 0, 0, 0};
  const unsigned short* arow = hs + (size_t)(R0 + n16) * Hn + q * 8;
#pragma unroll 4
  for (int ks = 0; ks < 32; ++ks) {
    bf16x8 A = *(const bf16x8*)(arow + ks * 32);
#pragma unroll
    for (int nt = 0; nt < 8; ++nt) {
      bf16x8 Bf = *(const bf16x8*)(WdT + (size_t)(nt * 16 + n16) * Hn + ks * 32 + q * 8);
      acc[nt] = __builtin_amdgcn_mfma_f32_16x16x32_bf16(A, Bf, acc[nt], 0, 0, 0);
    }
  }
#pragma unroll
  for (int nt = 0; nt < 8; ++nt) {
    int col = nt * 16 + n16;
    float bdv = bd[col];
#pragma unroll
    for (int r = 0; r < 4; ++r) {
      int R = R0 + q * 4 + r;
      int b = R & 63, t = R >> 6;
      out[((size_t)b * Tn + t) * 128 + col] = acc[nt][r] + bdv;
    }
  }
}

// ---------------- launcher ----------------
extern "C" void kernel_launch(void* const* d_in, const int* in_sizes, int n_in,
                              void* d_out, int out_size, void* d_ws, size_t ws_size,
                              hipStream_t stream) {
  const float* X    = (const float*)d_in[0];   // [64][512][128]
  const float* Wk   = (const float*)d_in[1];   // [1152][4096]
  const float* bias = (const float*)d_in[2];   // [4096]
  const float* Wd   = (const float*)d_in[3];   // [1024][128]
  const float* bd   = (const float*)d_in[4];   // [128]
  float* out = (float*)d_out;

  // ws layout (bytes):
  char* ws = (char*)d_ws;
  unsigned short* Xb  = (unsigned short*)(ws);              //  8,388,608
  unsigned short* WkT = (unsigned short*)(ws + 8388608);    //  9,437,184
  unsigned short* WdT = (unsigned short*)(ws + 17825792);   //    262,144
  unsigned short* hs  = (unsigned short*)(ws + 18087936);   // 67,108,864
  unsigned*       syn = (unsigned*)      (ws + 85196800);   //      4,096 (sync area)

  hipMemsetAsync(syn, 0, 4096, stream);
  cast_x_kernel<<<4096, 256, 0, stream>>>(X, Xb);
  transpose_cast_kernel<<<1152, 256, 0, stream>>>(Wk, WkT, 1152, 4096, 1152, 18);
  transpose_cast_kernel<<<32, 256, 0, stream>>>(Wd, WdT, 1024, 128, 1024, 16);
  lstm_kernel<<<NBLK, 256, 0, stream>>>(Xb, WkT, bias, hs, syn);
  dense_kernel<<<512, 256, 0, stream>>>(hs, WdT, bd, out);
}

// Round 5
// 3067.750 us; speedup vs baseline: 1.3406x; 1.3406x over previous
//
#include <hip/hip_runtime.h>
#include <math.h>

// Problem: B=64, T=512, I=128, H=1024, O=128; gates order i,j,f,o; relu activations.
#define Bsz 64
#define Tn  512
#define In  128
#define Hn  1024
#define KT  1152      // I + H
#define NBLK 128      // persistent blocks; each owns 8 hidden cols (x4 gates = 32 cols)

typedef __attribute__((ext_vector_type(8))) short bf16x8;   // 8 bf16 = 4 VGPRs (MFMA A/B frag)
typedef __attribute__((ext_vector_type(4))) short s16x4;
typedef __attribute__((ext_vector_type(4))) float f32x4;
typedef __attribute__((ext_vector_type(4))) int   i32x4;

// Raw buffer ops, cpol 17 = SC0|SC1 on gfx950 -> write-through / read-through at the
// IF/MALL coherence point (cross-XCD visible without cache-walk fences).
// [store path R0-proven; load-17 polling R1-proven to observe remote updates]
__device__ void llvm_amdgcn_raw_buffer_store_i16(short vdata, i32x4 srsrc, int voffset, int soffset, int cpol) __asm("llvm.amdgcn.raw.buffer.store.i16");
__device__ i32x4 llvm_amdgcn_raw_buffer_load_v4i32(i32x4 srsrc, int voffset, int soffset, int cpol) __asm("llvm.amdgcn.raw.buffer.load.v4i32");

__device__ __forceinline__ i32x4 make_srd(const void* p, int bytes) {
  i32x4 r;
  r.x = (int)(unsigned)(unsigned long long)p;
  r.y = (int)((unsigned long long)p >> 32);   // stride = 0
  r.z = bytes;                                // num_records (bytes when stride==0)
  r.w = 0x00020000;                           // raw dword access
  return r;
}

__device__ __forceinline__ bf16x8 as_bf16x8(i32x4 v) {
  union { i32x4 i; bf16x8 b; } u; u.i = v; return u.b;
}

__device__ __forceinline__ unsigned short f2bf(float f) {
  union { float f; unsigned u; } x; x.f = f;
  unsigned r = x.u + 0x7FFFu + ((x.u >> 16) & 1u);   // RNE
  return (unsigned short)(r >> 16);
}
__device__ __forceinline__ float sigmoidf_(float x) { return 1.0f / (1.0f + __expf(-x)); }

// ---------------- prep: X (fp32) -> Xb (bf16), elementwise ----------------
__global__ __launch_bounds__(256) void cast_x_kernel(const float* __restrict__ in,
                                                     unsigned short* __restrict__ out) {
  int i = blockIdx.x * 256 + threadIdx.x;
  f32x4 v = ((const f32x4*)in)[i];
  s16x4 o;
  o.x = (short)f2bf(v.x); o.y = (short)f2bf(v.y);
  o.z = (short)f2bf(v.z); o.w = (short)f2bf(v.w);
  ((s16x4*)out)[i] = o;
}

// -------- prep: transpose+cast fp32 [R][C] -> bf16 [C][ldo] (64x64 LDS tiles) --------
__global__ __launch_bounds__(256) void transpose_cast_kernel(const float* __restrict__ in,
                                                             unsigned short* __restrict__ out,
                                                             int R, int C, int ldo, int tilesR) {
  __shared__ unsigned short tile[64][73];
  int br = blockIdx.x % tilesR, bc = blockIdx.x / tilesR;
  int r0 = br << 6, c0 = bc << 6;
  for (int e = threadIdx.x; e < 4096; e += 256) {
    int r = e >> 6, c = e & 63;
    tile[r][c] = f2bf(in[(size_t)(r0 + r) * C + (c0 + c)]);
  }
  __syncthreads();
  for (int e = threadIdx.x; e < 4096; e += 256) {
    int c = e >> 6, r = e & 63;
    out[(size_t)(c0 + c) * ldo + (r0 + r)] = tile[r][c];
  }
}

// ---------------- persistent LSTM recurrence (data-is-the-flag) ----------------
// Block blk owns hidden cols j in [blk*8, blk*8+8), gate cols {j, H+j, 2H+j, 3H+j}.
// 8 waves = (2 batch-halves mh) x (4 K-quarters kq); B-frags register-resident.
// Wave kq owns x cols [32kq,+32) + h cols [256kq,+256): 1 x-step + 8 h-steps.
//
// Sync: NO counters, NO flags, NO atomics. hs is pre-poisoned 0xFF (bf16 sign=1);
// every real h value has sign=0 (h = sigmoid*relu >= 0). Consumers poll their own
// h A-fragments with cpol-17 loads until all sign bits clear -> the h load IS the
// flag observation. 2-byte stores can't tear; partial fragment visibility just
// retries. Producers keep R0's cpol-17 write-through stores; store acks are NEVER
// waited on (both barriers drain lgkm only) - they fly under the next step.
__global__ __launch_bounds__(512, 1) void lstm_kernel(
    const unsigned short* __restrict__ Xb,    // [64][512][128] bf16
    const unsigned short* __restrict__ WkT,   // [4096][1152]  bf16 (col-major-in-k)
    const float* __restrict__ bias,           // [4096]
    unsigned short* __restrict__ hs,          // [512][64][1024] bf16 (pre-poisoned 0xFF)
    unsigned* __restrict__ S)                 // (unused this round)
{
  __shared__ float Z4[4][64][36];             // per-kq partials [kq][batch][32 cols], ld 36
  const int tid = threadIdx.x;
  const int blk = blockIdx.x;
  const int w   = tid >> 6;
  const int mh  = w & 1;                      // batch half (32 rows)
  const int kq  = w >> 1;                     // K quarter: x[32kq,+32) + h[256kq,+256)
  const int l   = tid & 63, q = l >> 4, n16 = l & 15;

  const i32x4 hsrd = make_srd(hs, Tn * Bsz * Hn * 2);

  // ---- load register-resident B fragments (once) ----
  bf16x8 Bf[2][9];
#pragma unroll
  for (int nt = 0; nt < 2; ++nt) {
    int cl   = nt * 16 + n16;                                  // local col 0..31
    int gcol = (cl >> 3) * Hn + blk * 8 + (cl & 7);            // gate*1024 + j
    const unsigned short* bp = WkT + (size_t)gcol * KT;
    Bf[nt][0] = *(const bf16x8*)(bp + kq * 32 + q * 8);        // x slice
#pragma unroll
    for (int ks = 1; ks < 9; ++ks)                             // h slice
      Bf[nt][ks] = *(const bf16x8*)(bp + 128 + kq * 256 + (ks - 1) * 32 + q * 8);
  }

  // ---- epilogue constants: thread = (batch eb, col ej) ----
  const int eb = tid >> 3, ej = tid & 7;
  const float bi  = bias[           blk * 8 + ej];
  const float bg  = bias[    Hn   + blk * 8 + ej];
  const float bfg = bias[2 * Hn   + blk * 8 + ej] + 1.0f;      // TF forget bias
  const float bo  = bias[3 * Hn   + blk * 8 + ej];
  const int   hst_off = (eb * Hn + blk * 8 + ej) * 2;          // per-thread h store (byte, sans t)
  float cst = 0.0f;                                            // cell state, persistent in VGPR

  const int b0 = mh * 32 + n16;                                // A rows (two 16-batch tiles)
  const int b1 = b0 + 16;
  // per-lane h fragment byte offsets (sans t term): rows b0/b1, cols kq*256 + ks*32 + q*8
  const int ho0 = (b0 * Hn + kq * 256 + q * 8) * 2;
  const int ho1 = (b1 * Hn + kq * 256 + q * 8) * 2;

  for (int t = 0; t < Tn; ++t) {
    f32x4 a00 = {0,0,0,0}, a01 = {0,0,0,0}, a10 = {0,0,0,0}, a11 = {0,0,0,0};

    // x-part A-frags never depend on h: prefetch + MFMA before polling (ALL waves)
    bf16x8 X0 = *(const bf16x8*)(Xb + ((size_t)b0 * Tn + t) * In + kq * 32 + q * 8);
    bf16x8 X1 = *(const bf16x8*)(Xb + ((size_t)b1 * Tn + t) * In + kq * 32 + q * 8);
    a00 = __builtin_amdgcn_mfma_f32_16x16x32_bf16(X0, Bf[0][0], a00, 0, 0, 0);
    a01 = __builtin_amdgcn_mfma_f32_16x16x32_bf16(X0, Bf[1][0], a01, 0, 0, 0);
    a10 = __builtin_amdgcn_mfma_f32_16x16x32_bf16(X1, Bf[0][0], a10, 0, 0, 0);
    a11 = __builtin_amdgcn_mfma_f32_16x16x32_bf16(X1, Bf[1][0], a11, 0, 0, 0);

    if (t > 0) {
      // ---- data-poll: load this wave's 16 h fragments until all sign bits clear ----
      const int tb = (t - 1) * (Bsz * Hn * 2);
      i32x4 H0[8], H1[8];
      for (;;) {
        asm volatile("" ::: "memory");        // force re-load each attempt
#pragma unroll
        for (int ks = 0; ks < 8; ++ks) {
          H0[ks] = llvm_amdgcn_raw_buffer_load_v4i32(hsrd, tb + ho0 + ks * 64, 0, 17);
          H1[ks] = llvm_amdgcn_raw_buffer_load_v4i32(hsrd, tb + ho1 + ks * 64, 0, 17);
        }
        int bad = 0;
#pragma unroll
        for (int ks = 0; ks < 8; ++ks) {
          bad |= H0[ks].x | H0[ks].y | H0[ks].z | H0[ks].w;
          bad |= H1[ks].x | H1[ks].y | H1[ks].z | H1[ks].w;
        }
        if (__ballot(((unsigned)bad & 0x80008000u) == 0u) == ~0ull) break;
        __builtin_amdgcn_s_sleep(1);          // ~64cy backoff
      }
#pragma unroll
      for (int ks = 0; ks < 8; ++ks) {
        bf16x8 A0 = as_bf16x8(H0[ks]);
        bf16x8 A1 = as_bf16x8(H1[ks]);
        a00 = __builtin_amdgcn_mfma_f32_16x16x32_bf16(A0, Bf[0][ks + 1], a00, 0, 0, 0);
        a01 = __builtin_amdgcn_mfma_f32_16x16x32_bf16(A0, Bf[1][ks + 1], a01, 0, 0, 0);
        a10 = __builtin_amdgcn_mfma_f32_16x16x32_bf16(A1, Bf[0][ks + 1], a10, 0, 0, 0);
        a11 = __builtin_amdgcn_mfma_f32_16x16x32_bf16(A1, Bf[1][ks + 1], a11, 0, 0, 0);
      }
    }

    // ---- write per-kq partials ----
#pragma unroll
    for (int r = 0; r < 4; ++r) {
      int row = mh * 32 + q * 4 + r;
      Z4[kq][row     ][     n16] = a00[r];
      Z4[kq][row     ][16 + n16] = a01[r];
      Z4[kq][row + 16][     n16] = a10[r];
      Z4[kq][row + 16][16 + n16] = a11[r];
    }
    // barrier A: Z4 visible to all waves. LDS-only drain (NO vmcnt: h stores of
    // step t-1 keep flying; their acks are never on the critical path).
    asm volatile("s_waitcnt lgkmcnt(0)" ::: "memory");
    __builtin_amdgcn_s_barrier();

    // ---- gates + cell update: one (batch, col) per thread; sum 4 kq partials ----
    float zi = bi, zg = bg, zf = bfg, zo = bo;
#pragma unroll
    for (int k2 = 0; k2 < 4; ++k2) {
      zi += Z4[k2][eb][     ej];
      zg += Z4[k2][eb][ 8 + ej];
      zf += Z4[k2][eb][16 + ej];
      zo += Z4[k2][eb][24 + ej];
    }
    float ig = sigmoidf_(zi);
    float g  = fmaxf(zg, 0.0f);
    float ff = sigmoidf_(zf);
    float oo = sigmoidf_(zo);
    cst = ff * cst + ig * g;
    float hn = oo * fmaxf(cst, 0.0f);                          // >= 0: sign bit 0
    llvm_amdgcn_raw_buffer_store_i16((short)f2bf(hn), hsrd,
                                     t * (Bsz * Hn * 2) + hst_off, 0, 17);

    // barrier B: Z4 reads done before next step's Z4 writes. LDS-only drain.
    asm volatile("s_waitcnt lgkmcnt(0)" ::: "memory");
    __builtin_amdgcn_s_barrier();
  }
}

// ---------------- dense epilogue: out[b,t,:] = hs_row @ Wd + bd ----------------
__global__ __launch_bounds__(256) void dense_kernel(
    const unsigned short* __restrict__ hs,    // [32768][1024] bf16, row = t*64+b
    const unsigned short* __restrict__ WdT,   // [128][1024] bf16
    const float* __restrict__ bd,             // [128]
    float* __restrict__ out)                  // [64][512][128] fp32
{
  const int tid = threadIdx.x;
  const int w = tid >> 6, l = tid & 63, q = l >> 4, n16 = l & 15;
  const int R0 = blockIdx.x * 64 + w * 16;
  f32x4 acc[8];
#pragma unroll
  for (int i = 0; i < 8; ++i) acc[i] = (f32x4){0, 0, 0, 0};
  const unsigned short* arow = hs + (size_t)(R0 + n16) * Hn + q * 8;
#pragma unroll 4
  for (int ks = 0; ks < 32; ++ks) {
    bf16x8 A = *(const bf16x8*)(arow + ks * 32);
#pragma unroll
    for (int nt = 0; nt < 8; ++nt) {
      bf16x8 Bf = *(const bf16x8*)(WdT + (size_t)(nt * 16 + n16) * Hn + ks * 32 + q * 8);
      acc[nt] = __builtin_amdgcn_mfma_f32_16x16x32_bf16(A, Bf, acc[nt], 0, 0, 0);
    }
  }
#pragma unroll
  for (int nt = 0; nt < 8; ++nt) {
    int col = nt * 16 + n16;
    float bdv = bd[col];
#pragma unroll
    for (int r = 0; r < 4; ++r) {
      int R = R0 + q * 4 + r;
      int b = R & 63, t = R >> 6;
      out[((size_t)b * Tn + t) * 128 + col] = acc[nt][r] + bdv;
    }
  }
}

// ---------------- launcher ----------------
extern "C" void kernel_launch(void* const* d_in, const int* in_sizes, int n_in,
                              void* d_out, int out_size, void* d_ws, size_t ws_size,
                              hipStream_t stream) {
  const float* X    = (const float*)d_in[0];   // [64][512][128]
  const float* Wk   = (const float*)d_in[1];   // [1152][4096]
  const float* bias = (const float*)d_in[2];   // [4096]
  const float* Wd   = (const float*)d_in[3];   // [1024][128]
  const float* bd   = (const float*)d_in[4];   // [128]
  float* out = (float*)d_out;

  // ws layout (bytes):
  char* ws = (char*)d_ws;
  unsigned short* Xb  = (unsigned short*)(ws);              //  8,388,608
  unsigned short* WkT = (unsigned short*)(ws + 8388608);    //  9,437,184
  unsigned short* WdT = (unsigned short*)(ws + 17825792);   //    262,144
  unsigned short* hs  = (unsigned short*)(ws + 18087936);   // 67,108,864
  unsigned*       syn = (unsigned*)      (ws + 85196800);   //      4,096 (sync area)

  // Pre-poison hs: 0xFF bytes = bf16 sign-bit set = "not yet written" sentinel.
  hipMemsetAsync(hs, 0xFF, 67108864, stream);
  hipMemsetAsync(syn, 0, 4096, stream);
  cast_x_kernel<<<4096, 256, 0, stream>>>(X, Xb);
  transpose_cast_kernel<<<1152, 256, 0, stream>>>(Wk, WkT, 1152, 4096, 1152, 18);
  transpose_cast_kernel<<<32, 256, 0, stream>>>(Wd, WdT, 1024, 128, 1024, 16);
  lstm_kernel<<<NBLK, 512, 0, stream>>>(Xb, WkT, bias, hs, syn);
  dense_kernel<<<512, 256, 0, stream>>>(hs, WdT, bd, out);
}

// Round 6
// 2960.739 us; speedup vs baseline: 1.3891x; 1.0361x over previous
//
#include <hip/hip_runtime.h>
#include <math.h>

// Problem: B=64, T=512, I=128, H=1024, O=128; gates order i,j,f,o; relu activations.
#define Bsz 64
#define Tn  512
#define In  128
#define Hn  1024
#define KT  1152      // I + H
#define NBLK 128      // persistent blocks; each owns 8 hidden cols (x4 gates = 32 cols)

typedef __attribute__((ext_vector_type(8))) short bf16x8;   // 8 bf16 = 4 VGPRs (MFMA A/B frag)
typedef __attribute__((ext_vector_type(4))) short s16x4;
typedef __attribute__((ext_vector_type(4))) float f32x4;
typedef __attribute__((ext_vector_type(4))) int   i32x4;

// Raw buffer ops, cpol 17 = SC0|SC1 on gfx950 -> write-through / read-through at the
// IF/MALL coherence point (cross-XCD visible without cache-walk fences).
// [store path R0-proven; load-17 polling R1/R5-proven to observe remote updates]
__device__ void llvm_amdgcn_raw_buffer_store_i16(short vdata, i32x4 srsrc, int voffset, int soffset, int cpol) __asm("llvm.amdgcn.raw.buffer.store.i16");
__device__ void llvm_amdgcn_raw_buffer_store_i32(int vdata, i32x4 srsrc, int voffset, int soffset, int cpol) __asm("llvm.amdgcn.raw.buffer.store.i32");
__device__ i32x4 llvm_amdgcn_raw_buffer_load_v4i32(i32x4 srsrc, int voffset, int soffset, int cpol) __asm("llvm.amdgcn.raw.buffer.load.v4i32");

__device__ __forceinline__ i32x4 make_srd(const void* p, int bytes) {
  i32x4 r;
  r.x = (int)(unsigned)(unsigned long long)p;
  r.y = (int)((unsigned long long)p >> 32);   // stride = 0
  r.z = bytes;                                // num_records (bytes when stride==0)
  r.w = 0x00020000;                           // raw dword access
  return r;
}

__device__ __forceinline__ unsigned short f2bf(float f) {
  union { float f; unsigned u; } x; x.f = f;
  unsigned r = x.u + 0x7FFFu + ((x.u >> 16) & 1u);   // RNE
  return (unsigned short)(r >> 16);
}
__device__ __forceinline__ float sigmoidf_(float x) { return 1.0f / (1.0f + __expf(-x)); }

// ---------------- prep: X (fp32) -> Xb (bf16), elementwise ----------------
__global__ __launch_bounds__(256) void cast_x_kernel(const float* __restrict__ in,
                                                     unsigned short* __restrict__ out) {
  int i = blockIdx.x * 256 + threadIdx.x;
  f32x4 v = ((const f32x4*)in)[i];
  s16x4 o;
  o.x = (short)f2bf(v.x); o.y = (short)f2bf(v.y);
  o.z = (short)f2bf(v.z); o.w = (short)f2bf(v.w);
  ((s16x4*)out)[i] = o;
}

// -------- prep: transpose+cast fp32 [R][C] -> bf16 [C][ldo] (64x64 LDS tiles) --------
__global__ __launch_bounds__(256) void transpose_cast_kernel(const float* __restrict__ in,
                                                             unsigned short* __restrict__ out,
                                                             int R, int C, int ldo, int tilesR) {
  __shared__ unsigned short tile[64][73];
  int br = blockIdx.x % tilesR, bc = blockIdx.x / tilesR;
  int r0 = br << 6, c0 = bc << 6;
  for (int e = threadIdx.x; e < 4096; e += 256) {
    int r = e >> 6, c = e & 63;
    tile[r][c] = f2bf(in[(size_t)(r0 + r) * C + (c0 + c)]);
  }
  __syncthreads();
  for (int e = threadIdx.x; e < 4096; e += 256) {
    int c = e >> 6, r = e & 63;
    out[(size_t)(c0 + c) * ldo + (r0 + r)] = tile[r][c];
  }
}

// ---------------- persistent LSTM recurrence (per-wave sentinels) ----------------
// Block blk owns hidden cols j in [blk*8, blk*8+8), gate cols {j, H+j, 2H+j, 3H+j}.
// 8 waves = (2 batch-halves mh) x (4 K-quarters kq); B-frags register-resident.
// Wave kq owns x cols [32kq,+32) + h cols [256kq,+256): 1 x-step + 8 h-steps.
//
// Sync: NO atomics, NO block-wide drains. Producer wave stores its 64 h elems
// (cpol17), waits ITS OWN vmcnt(0) (wave-level: covers all 64 lanes' stores),
// lane0 posts sentinel word S[blk*8+w] = t+1 (cpol17). Consumers poll ONLY the
// 128 sentinel words they depend on (32 lanes x dwordx4 = 512B/sweep, 32x less
// MALL poll traffic than R5's data-poll), then load h PLAIN (L2-cached; each
// 128B line crosses MALL->L2 once per XCD). Barriers stay lgkm-only.
__global__ __launch_bounds__(512, 1) void lstm_kernel(
    const unsigned short* __restrict__ Xb,    // [64][512][128] bf16
    const unsigned short* __restrict__ WkT,   // [4096][1152]  bf16 (col-major-in-k)
    const float* __restrict__ bias,           // [4096]
    unsigned short* __restrict__ hs,          // [512][64][1024] bf16 (output history)
    unsigned* __restrict__ S)                 // sentinels: 128 blk x 8 wave x u32 (4 KB)
{
  __shared__ float Z4[4][64][36];             // per-kq partials [kq][batch][32 cols], ld 36
  const int tid = threadIdx.x;
  const int blk = blockIdx.x;
  const int w   = tid >> 6;
  const int mh  = w & 1;                      // batch half (32 rows)
  const int kq  = w >> 1;                     // K quarter: x[32kq,+32) + h[256kq,+256)
  const int l   = tid & 63, q = l >> 4, n16 = l & 15;

  const i32x4 hsrd = make_srd(hs, Tn * Bsz * Hn * 2);
  const i32x4 ssrd = make_srd(S, 4096);

  // ---- load register-resident B fragments (once) ----
  bf16x8 Bf[2][9];
#pragma unroll
  for (int nt = 0; nt < 2; ++nt) {
    int cl   = nt * 16 + n16;                                  // local col 0..31
    int gcol = (cl >> 3) * Hn + blk * 8 + (cl & 7);            // gate*1024 + j
    const unsigned short* bp = WkT + (size_t)gcol * KT;
    Bf[nt][0] = *(const bf16x8*)(bp + kq * 32 + q * 8);        // x slice
#pragma unroll
    for (int ks = 1; ks < 9; ++ks)                             // h slice
      Bf[nt][ks] = *(const bf16x8*)(bp + 128 + kq * 256 + (ks - 1) * 32 + q * 8);
  }

  // ---- epilogue constants: thread = (batch eb, col ej) ----
  const int eb = tid >> 3, ej = tid & 7;                       // wave w covers eb in [8w,8w+8)
  const float bi  = bias[           blk * 8 + ej];
  const float bg  = bias[    Hn   + blk * 8 + ej];
  const float bfg = bias[2 * Hn   + blk * 8 + ej] + 1.0f;      // TF forget bias
  const float bo  = bias[3 * Hn   + blk * 8 + ej];
  const int   hst_off = (eb * Hn + blk * 8 + ej) * 2;          // per-thread h store (byte, sans t)
  float cst = 0.0f;                                            // cell state, persistent in VGPR

  const int b0 = mh * 32 + n16;                                // A rows (two 16-batch tiles)
  const int b1 = b0 + 16;
  // sentinel poll address: producer block s = 32kq + (l&31), row-waves [4mh, 4mh+4)
  // -> words s*8 + 4mh .. +3 -> one dwordx4 per lane (2 lanes per block, harmless dup)
  const int so = ((32 * kq + (l & 31)) * 8 + 4 * mh) * 4;

  for (int t = 0; t < Tn; ++t) {
    f32x4 a00 = {0,0,0,0}, a01 = {0,0,0,0}, a10 = {0,0,0,0}, a11 = {0,0,0,0};

    // x-part A-frags never depend on h: prefetch + MFMA before polling (ALL waves)
    bf16x8 X0 = *(const bf16x8*)(Xb + ((size_t)b0 * Tn + t) * In + kq * 32 + q * 8);
    bf16x8 X1 = *(const bf16x8*)(Xb + ((size_t)b1 * Tn + t) * In + kq * 32 + q * 8);
    a00 = __builtin_amdgcn_mfma_f32_16x16x32_bf16(X0, Bf[0][0], a00, 0, 0, 0);
    a01 = __builtin_amdgcn_mfma_f32_16x16x32_bf16(X0, Bf[1][0], a01, 0, 0, 0);
    a10 = __builtin_amdgcn_mfma_f32_16x16x32_bf16(X1, Bf[0][0], a10, 0, 0, 0);
    a11 = __builtin_amdgcn_mfma_f32_16x16x32_bf16(X1, Bf[1][0], a11, 0, 0, 0);

    if (t > 0) {
      // ---- sentinel poll: 32 producer blocks x 4 row-waves, 512B per sweep ----
      const unsigned tgt = (unsigned)t;       // sentinel v => h(0..v-1) visible
      for (;;) {
        asm volatile("" ::: "memory");        // force re-load each attempt
        i32x4 v = llvm_amdgcn_raw_buffer_load_v4i32(ssrd, so, 0, 17);
        unsigned ma = (unsigned)v.x < (unsigned)v.y ? (unsigned)v.x : (unsigned)v.y;
        unsigned mc = (unsigned)v.z < (unsigned)v.w ? (unsigned)v.z : (unsigned)v.w;
        ma = ma < mc ? ma : mc;
        if (__ballot(ma >= tgt) == ~0ull) break;
        __builtin_amdgcn_s_sleep(1);          // ~64cy backoff
      }
      // ---- h part: plain (cached) loads -- each fresh line crosses MALL once/XCD ----
      const unsigned short* hrow = hs + (size_t)(t - 1) * (Bsz * Hn);
#pragma unroll
      for (int ks = 0; ks < 8; ++ks) {
        int kh = kq * 256 + ks * 32 + q * 8;                   // h col
        bf16x8 A0 = *(const bf16x8*)(hrow + (size_t)b0 * Hn + kh);
        bf16x8 A1 = *(const bf16x8*)(hrow + (size_t)b1 * Hn + kh);
        a00 = __builtin_amdgcn_mfma_f32_16x16x32_bf16(A0, Bf[0][ks + 1], a00, 0, 0, 0);
        a01 = __builtin_amdgcn_mfma_f32_16x16x32_bf16(A0, Bf[1][ks + 1], a01, 0, 0, 0);
        a10 = __builtin_amdgcn_mfma_f32_16x16x32_bf16(A1, Bf[0][ks + 1], a10, 0, 0, 0);
        a11 = __builtin_amdgcn_mfma_f32_16x16x32_bf16(A1, Bf[1][ks + 1], a11, 0, 0, 0);
      }
    }

    // ---- write per-kq partials ----
#pragma unroll
    for (int r = 0; r < 4; ++r) {
      int row = mh * 32 + q * 4 + r;
      Z4[kq][row     ][     n16] = a00[r];
      Z4[kq][row     ][16 + n16] = a01[r];
      Z4[kq][row + 16][     n16] = a10[r];
      Z4[kq][row + 16][16 + n16] = a11[r];
    }
    // barrier A: Z4 visible to all waves. LDS-only drain (h/sentinel store acks of
    // the previous step keep flying; never on the critical path here).
    asm volatile("s_waitcnt lgkmcnt(0)" ::: "memory");
    __builtin_amdgcn_s_barrier();

    // ---- gates + cell update: one (batch, col) per thread; sum 4 kq partials ----
    float zi = bi, zg = bg, zf = bfg, zo = bo;
#pragma unroll
    for (int k2 = 0; k2 < 4; ++k2) {
      zi += Z4[k2][eb][     ej];
      zg += Z4[k2][eb][ 8 + ej];
      zf += Z4[k2][eb][16 + ej];
      zo += Z4[k2][eb][24 + ej];
    }
    float ig = sigmoidf_(zi);
    float g  = fmaxf(zg, 0.0f);
    float ff = sigmoidf_(zf);
    float oo = sigmoidf_(zo);
    cst = ff * cst + ig * g;
    float hn = oo * fmaxf(cst, 0.0f);
    llvm_amdgcn_raw_buffer_store_i16((short)f2bf(hn), hsrd,
                                     t * (Bsz * Hn * 2) + hst_off, 0, 17);

    // ---- per-wave sentinel: wait OWN stores acked (wave-level vmcnt covers all
    // 64 lanes), then lane0 posts S[blk*8+w] = t+1. No block-wide drain. ----
    asm volatile("s_waitcnt vmcnt(0)" ::: "memory");
    if (t < Tn - 1 && l == 0)
      llvm_amdgcn_raw_buffer_store_i32((int)(t + 1), ssrd, (blk * 8 + w) * 4, 0, 17);

    // barrier B: Z4 reads done before next step's Z4 writes. LDS-only drain.
    asm volatile("s_waitcnt lgkmcnt(0)" ::: "memory");
    __builtin_amdgcn_s_barrier();
  }
}

// ---------------- dense epilogue: out[b,t,:] = hs_row @ Wd + bd ----------------
__global__ __launch_bounds__(256) void dense_kernel(
    const unsigned short* __restrict__ hs,    // [32768][1024] bf16, row = t*64+b
    const unsigned short* __restrict__ WdT,   // [128][1024] bf16
    const float* __restrict__ bd,             // [128]
    float* __restrict__ out)                  // [64][512][128] fp32
{
  const int tid = threadIdx.x;
  const int w = tid >> 6, l = tid & 63, q = l >> 4, n16 = l & 15;
  const int R0 = blockIdx.x * 64 + w * 16;
  f32x4 acc[8];
#pragma unroll
  for (int i = 0; i < 8; ++i) acc[i] = (f32x4){0, 0, 0, 0};
  const unsigned short* arow = hs + (size_t)(R0 + n16) * Hn + q * 8;
#pragma unroll 4
  for (int ks = 0; ks < 32; ++ks) {
    bf16x8 A = *(const bf16x8*)(arow + ks * 32);
#pragma unroll
    for (int nt = 0; nt < 8; ++nt) {
      bf16x8 Bf = *(const bf16x8*)(WdT + (size_t)(nt * 16 + n16) * Hn + ks * 32 + q * 8);
      acc[nt] = __builtin_amdgcn_mfma_f32_16x16x32_bf16(A, Bf, acc[nt], 0, 0, 0);
    }
  }
#pragma unroll
  for (int nt = 0; nt < 8; ++nt) {
    int col = nt * 16 + n16;
    float bdv = bd[col];
#pragma unroll
    for (int r = 0; r < 4; ++r) {
      int R = R0 + q * 4 + r;
      int b = R & 63, t = R >> 6;
      out[((size_t)b * Tn + t) * 128 + col] = acc[nt][r] + bdv;
    }
  }
}

// ---------------- launcher ----------------
extern "C" void kernel_launch(void* const* d_in, const int* in_sizes, int n_in,
                              void* d_out, int out_size, void* d_ws, size_t ws_size,
                              hipStream_t stream) {
  const float* X    = (const float*)d_in[0];   // [64][512][128]
  const float* Wk   = (const float*)d_in[1];   // [1152][4096]
  const float* bias = (const float*)d_in[2];   // [4096]
  const float* Wd   = (const float*)d_in[3];   // [1024][128]
  const float* bd   = (const float*)d_in[4];   // [128]
  float* out = (float*)d_out;

  // ws layout (bytes):
  char* ws = (char*)d_ws;
  unsigned short* Xb  = (unsigned short*)(ws);              //  8,388,608
  unsigned short* WkT = (unsigned short*)(ws + 8388608);    //  9,437,184
  unsigned short* WdT = (unsigned short*)(ws + 17825792);   //    262,144
  unsigned short* hs  = (unsigned short*)(ws + 18087936);   // 67,108,864
  unsigned*       syn = (unsigned*)      (ws + 85196800);   //      4,096 (sentinels)

  hipMemsetAsync(syn, 0, 4096, stream);
  cast_x_kernel<<<4096, 256, 0, stream>>>(X, Xb);
  transpose_cast_kernel<<<1152, 256, 0, stream>>>(Wk, WkT, 1152, 4096, 1152, 18);
  transpose_cast_kernel<<<32, 256, 0, stream>>>(Wd, WdT, 1024, 128, 1024, 16);
  lstm_kernel<<<NBLK, 512, 0, stream>>>(Xb, WkT, bias, hs, syn);
  dense_kernel<<<512, 256, 0, stream>>>(hs, WdT, bd, out);
}